// Round 1
// baseline (5611.855 us; speedup 1.0000x reference)
//
#include <hip/hip_runtime.h>
#include <math.h>

#define NA 50000
#define NP 1000000
#define FD 128
#define KD 64
#define NB 5
#define NRI_ 3
#define NRF_ 2

__device__ __forceinline__ float sspf(float x) {
    // shifted softplus: max(x,0) + log1p(exp(-|x|)) - log(2)
    float ax = fabsf(x);
    return fmaxf(x, 0.0f) + log1pf(__expf(-ax)) - 0.69314718055994530942f;
}

__device__ __forceinline__ void fma4(float4& a, float s, const float4 w) {
    a.x = fmaf(s, w.x, a.x);
    a.y = fmaf(s, w.y, a.y);
    a.z = fmaf(s, w.z, a.z);
    a.w = fmaf(s, w.w, a.w);
}

// C[r,0:128] = post( pre(A[r,:]) @ W[128x128] + bias ) + (add ? (u ? u*add : add) : 0)
// tile: 64 rows x 128 cols per workgroup of 256 threads; thread = 8 rows x 4 cols
__launch_bounds__(256, 2)
__global__ void gemm_atoms(const float* __restrict__ A,
                           const float* __restrict__ W,
                           const float* __restrict__ bias,
                           const float* __restrict__ add,
                           const float* __restrict__ uvec,
                           float* __restrict__ C,
                           int nrows, int preSSP, int postSSP)
{
    __shared__ float A_s[64 * 132];   // 64 rows x 128 k, stride 132
    __shared__ float W_s[64 * 128];   // half of W (64 k) at a time

    const int tid = threadIdx.x;
    const int row0 = blockIdx.x * 64;
    const int tx = tid & 31;
    const int ty = tid >> 5;
    const int tx4 = tx * 4;

    // ---- load A tile (apply preSSP), 8 float4 per thread, coalesced ----
#pragma unroll
    for (int i = 0; i < 8; ++i) {
        int f = i * 256 + tid;          // float4 index 0..2047
        int r = f >> 5;                 // 0..63
        int cq = (f & 31) * 4;          // 0..124
        float4 v = make_float4(0.f, 0.f, 0.f, 0.f);
        if (row0 + r < nrows) {
            v = *(const float4*)&A[(size_t)(row0 + r) * FD + cq];
            if (preSSP) { v.x = sspf(v.x); v.y = sspf(v.y); v.z = sspf(v.z); v.w = sspf(v.w); }
        }
        *(float4*)&A_s[r * 132 + cq] = v;
    }

    float4 acc[8];
#pragma unroll
    for (int i = 0; i < 8; ++i) acc[i] = make_float4(0.f, 0.f, 0.f, 0.f);

    for (int c = 0; c < 2; ++c) {
        if (c) __syncthreads();         // all reads of previous W chunk done
#pragma unroll
        for (int i = 0; i < 8; ++i) {
            int f = i * 256 + tid;
            int k = f >> 5;             // 0..63
            int cq = (f & 31) * 4;
            *(float4*)&W_s[k * 128 + cq] = *(const float4*)&W[(size_t)(c * 64 + k) * FD + cq];
        }
        __syncthreads();                // W chunk (and A tile for c==0) visible
        const int cb = c * 64;
#pragma unroll 4
        for (int k = 0; k < 64; k += 4) {
            float4 w0 = *(float4*)&W_s[(k + 0) * 128 + tx4];
            float4 w1 = *(float4*)&W_s[(k + 1) * 128 + tx4];
            float4 w2 = *(float4*)&W_s[(k + 2) * 128 + tx4];
            float4 w3 = *(float4*)&W_s[(k + 3) * 128 + tx4];
#pragma unroll
            for (int i = 0; i < 8; ++i) {
                float4 a = *(float4*)&A_s[(ty * 8 + i) * 132 + cb + k];
                fma4(acc[i], a.x, w0);
                fma4(acc[i], a.y, w1);
                fma4(acc[i], a.z, w2);
                fma4(acc[i], a.w, w3);
            }
        }
    }

    float4 bv = *(const float4*)&bias[tx4];
    float4 uv = make_float4(1.f, 1.f, 1.f, 1.f);
    if (uvec) uv = *(const float4*)&uvec[tx4];

#pragma unroll
    for (int i = 0; i < 8; ++i) {
        int r = row0 + ty * 8 + i;
        if (r >= nrows) continue;
        float4 v = acc[i];
        v.x += bv.x; v.y += bv.y; v.z += bv.z; v.w += bv.w;
        if (postSSP) { v.x = sspf(v.x); v.y = sspf(v.y); v.z = sspf(v.z); v.w = sspf(v.w); }
        if (add) {
            float4 av = *(const float4*)&add[(size_t)r * FD + tx4];
            v.x = fmaf(uv.x, av.x, v.x);
            v.y = fmaf(uv.y, av.y, v.y);
            v.z = fmaf(uv.z, av.z, v.z);
            v.w = fmaf(uv.w, av.w, v.w);
        }
        *(float4*)&C[(size_t)r * FD + tx4] = v;
    }
}

// Per pair p: g = (cutoff[p]*rbf[p]) @ Wg  (128 wide), msg = g * xj[idx_j[p]],
// m[idx_i[p]] += msg (segment sum; idx_i sorted -> run-accumulate + atomic flush).
// Tile: 128 pairs per workgroup of 256 threads.
__launch_bounds__(256, 2)
__global__ void pair_kernel(const float* __restrict__ rbfs,
                            const float* __restrict__ cutoffs,
                            const int* __restrict__ idx_i,
                            const int* __restrict__ idx_j,
                            const float* __restrict__ Wg,   // [64][128], already offset by block
                            const float* __restrict__ xj,   // [NA][128]
                            float* __restrict__ m)          // [NA][128], accumulated into
{
    __shared__ float smem[128 * 68 + 64 * 128];  // desc[128][68] + wg[64][128]; phase2: msg[128][128]
    float* desc_s = smem;
    float* wg_s = smem + 128 * 68;
    float* msg_s = smem;                         // aliases desc+wg after GEMM
    __shared__ int ii_s[128];
    __shared__ int jj_s[128];

    const int tid = threadIdx.x;
    const long long p0 = (long long)blockIdx.x * 128;

    // ---- load desc = cutoff * rbf : 128 pairs x 64 K ----
#pragma unroll
    for (int i = 0; i < 8; ++i) {
        int f = i * 256 + tid;      // float4 idx 0..2047
        int p = f >> 4;             // 0..127
        int kq = (f & 15) * 4;      // 0..60
        long long pg = p0 + p;
        float4 v = make_float4(0.f, 0.f, 0.f, 0.f);
        if (pg < NP) {
            v = *(const float4*)&rbfs[pg * KD + kq];
            float cu = cutoffs[pg];
            v.x *= cu; v.y *= cu; v.z *= cu; v.w *= cu;
        }
        *(float4*)&desc_s[p * 68 + kq] = v;
    }
    // ---- load Wg [64][128] ----
#pragma unroll
    for (int i = 0; i < 8; ++i) {
        int f = i * 256 + tid;
        int k = f >> 5;
        int cq = (f & 31) * 4;
        *(float4*)&wg_s[k * 128 + cq] = *(const float4*)&Wg[(size_t)k * FD + cq];
    }
    if (tid < 128) {
        long long pg = p0 + tid;
        ii_s[tid] = (pg < NP) ? idx_i[pg] : -1;
        jj_s[tid] = (pg < NP) ? idx_j[pg] : 0;
    }
    __syncthreads();

    // ---- GEMM: [128 pairs][64] @ [64][128]; thread = 8 pairs (stride 16) x (4+4) cols ----
    const int tx = tid & 15;
    const int ty = tid >> 4;
    const int c0 = tx * 4;
    const int c1 = c0 + 64;

    float4 acc0[8], acc1[8];
#pragma unroll
    for (int i = 0; i < 8; ++i) {
        acc0[i] = make_float4(0.f, 0.f, 0.f, 0.f);
        acc1[i] = make_float4(0.f, 0.f, 0.f, 0.f);
    }

#pragma unroll 2
    for (int k = 0; k < 64; k += 4) {
        float4 w00 = *(float4*)&wg_s[(k + 0) * 128 + c0];
        float4 w01 = *(float4*)&wg_s[(k + 1) * 128 + c0];
        float4 w02 = *(float4*)&wg_s[(k + 2) * 128 + c0];
        float4 w03 = *(float4*)&wg_s[(k + 3) * 128 + c0];
        float4 w10 = *(float4*)&wg_s[(k + 0) * 128 + c1];
        float4 w11 = *(float4*)&wg_s[(k + 1) * 128 + c1];
        float4 w12 = *(float4*)&wg_s[(k + 2) * 128 + c1];
        float4 w13 = *(float4*)&wg_s[(k + 3) * 128 + c1];
#pragma unroll
        for (int i = 0; i < 8; ++i) {
            float4 a = *(float4*)&desc_s[(ty + 16 * i) * 68 + k];
            fma4(acc0[i], a.x, w00); fma4(acc0[i], a.y, w01);
            fma4(acc0[i], a.z, w02); fma4(acc0[i], a.w, w03);
            fma4(acc1[i], a.x, w10); fma4(acc1[i], a.y, w11);
            fma4(acc1[i], a.z, w12); fma4(acc1[i], a.w, w13);
        }
    }

    __syncthreads();   // desc/wg reads complete; smem may be reused as msg

    // ---- epilogue: msg = g * xj[idx_j[p]] -> LDS ----
#pragma unroll
    for (int i = 0; i < 8; ++i) {
        int p = ty + 16 * i;
        int jrow = jj_s[p];
        float4 x0 = *(const float4*)&xj[(size_t)jrow * FD + c0];
        float4 x1 = *(const float4*)&xj[(size_t)jrow * FD + c1];
        float4 m0 = acc0[i];
        float4 m1 = acc1[i];
        m0.x *= x0.x; m0.y *= x0.y; m0.z *= x0.z; m0.w *= x0.w;
        m1.x *= x1.x; m1.y *= x1.y; m1.z *= x1.z; m1.w *= x1.w;
        *(float4*)&msg_s[p * 128 + c0] = m0;
        *(float4*)&msg_s[p * 128 + c1] = m1;
    }
    __syncthreads();

    // ---- segment-sum scan: 2 halves x 128 cols; run-accumulate on sorted idx_i ----
    const int col = tid & 127;
    const int half = tid >> 7;
    const int ps = half * 64;
    float accum = 0.f;
    int cur = ii_s[ps];
    for (int q = 0; q < 64; ++q) {
        int p = ps + q;
        int a = ii_s[p];
        if (a != cur) {
            if (cur >= 0) atomicAdd(&m[(size_t)cur * FD + col], accum);
            accum = 0.f;
            cur = a;
        }
        accum += msg_s[p * 128 + col];
    }
    if (cur >= 0) atomicAdd(&m[(size_t)cur * FD + col], accum);
}

extern "C" void kernel_launch(void* const* d_in, const int* in_sizes, int n_in,
                              void* d_out, int out_size, void* d_ws, size_t ws_size,
                              hipStream_t stream)
{
    const float* features = (const float*)d_in[0];
    const float* cutoffs  = (const float*)d_in[1];
    const float* rbfs     = (const float*)d_in[2];
    const int*   idx_i    = (const int*)d_in[3];
    const int*   idx_j    = (const int*)d_in[4];
    const float* Wg   = (const float*)d_in[5];
    const float* Wi   = (const float*)d_in[6];
    const float* bi   = (const float*)d_in[7];
    const float* Wj   = (const float*)d_in[8];
    const float* bj   = (const float*)d_in[9];
    const float* Wr1  = (const float*)d_in[10];
    const float* br1  = (const float*)d_in[11];
    const float* Wr2  = (const float*)d_in[12];
    const float* br2  = (const float*)d_in[13];
    const float* Wout = (const float*)d_in[14];
    const float* bout = (const float*)d_in[15];
    const float* u    = (const float*)d_in[16];
    const float* Wf1  = (const float*)d_in[17];
    const float* bf1  = (const float*)d_in[18];
    const float* Wf2  = (const float*)d_in[19];
    const float* bf2  = (const float*)d_in[20];
    float* out = (float*)d_out;

    const size_t NF = (size_t)NA * FD;
    float* mbuf  = (float*)d_ws;
    float* tbuf  = mbuf + NF;
    float* xjbuf = tbuf + NF;

    const int gA = (NA + 63) / 64;       // 782
    const int gP = (NP + 127) / 128;     // 7813
    dim3 blk(256);

    const float* x = features;
    for (int b = 0; b < NB; ++b) {
        const float* Wi_b   = Wi   + (size_t)b * FD * FD;
        const float* bi_b   = bi   + (size_t)b * FD;
        const float* Wj_b   = Wj   + (size_t)b * FD * FD;
        const float* bj_b   = bj   + (size_t)b * FD;
        const float* Wg_b   = Wg   + (size_t)b * KD * FD;
        const float* Wout_b = Wout + (size_t)b * FD * FD;
        const float* bout_b = bout + (size_t)b * FD;
        const float* u_b    = u    + (size_t)b * FD;
        float* xout = out + (size_t)b * NF;

        // xi = ssp(ssp(x)@Wi + bi)  -> mbuf   (m starts as xi)
        gemm_atoms<<<gA, blk, 0, stream>>>(x, Wi_b, bi_b, nullptr, nullptr, mbuf, NA, 1, 1);
        // xj = ssp(ssp(x)@Wj + bj)  -> xjbuf
        gemm_atoms<<<gA, blk, 0, stream>>>(x, Wj_b, bj_b, nullptr, nullptr, xjbuf, NA, 1, 1);
        // m += segment_sum(g * xj[idx_j], idx_i)
        pair_kernel<<<gP, blk, 0, stream>>>(rbfs, cutoffs, idx_i, idx_j, Wg_b, xjbuf, mbuf);
        // interaction residuals: m = m + ssp(ssp(m)@Wr1+br1)@Wr2 + br2
        for (int r = 0; r < NRI_; ++r) {
            const float* Wr1_br = Wr1 + ((size_t)b * NRI_ + r) * FD * FD;
            const float* br1_br = br1 + ((size_t)b * NRI_ + r) * FD;
            const float* Wr2_br = Wr2 + ((size_t)b * NRI_ + r) * FD * FD;
            const float* br2_br = br2 + ((size_t)b * NRI_ + r) * FD;
            gemm_atoms<<<gA, blk, 0, stream>>>(mbuf, Wr1_br, br1_br, nullptr, nullptr, tbuf, NA, 1, 1);
            gemm_atoms<<<gA, blk, 0, stream>>>(tbuf, Wr2_br, br2_br, mbuf, nullptr, mbuf, NA, 0, 0);
        }
        // x_new = u*x + ssp(m)@Wout + bout  -> out slice b
        gemm_atoms<<<gA, blk, 0, stream>>>(mbuf, Wout_b, bout_b, x, u_b, xout, NA, 1, 0);
        // feature residuals: x = x + ssp(ssp(x)@Wf1+bf1)@Wf2 + bf2
        for (int r = 0; r < NRF_; ++r) {
            const float* Wf1_br = Wf1 + ((size_t)b * NRF_ + r) * FD * FD;
            const float* bf1_br = bf1 + ((size_t)b * NRF_ + r) * FD;
            const float* Wf2_br = Wf2 + ((size_t)b * NRF_ + r) * FD * FD;
            const float* bf2_br = bf2 + ((size_t)b * NRF_ + r) * FD;
            gemm_atoms<<<gA, blk, 0, stream>>>(xout, Wf1_br, bf1_br, nullptr, nullptr, tbuf, NA, 1, 1);
            gemm_atoms<<<gA, blk, 0, stream>>>(tbuf, Wf2_br, bf2_br, xout, nullptr, xout, NA, 0, 0);
        }
        x = xout;
    }
}

// Round 2
// 4269.238 us; speedup vs baseline: 1.3145x; 1.3145x over previous
//
#include <hip/hip_runtime.h>
#include <math.h>

#define NA 50000
#define NP 1000000
#define FD 128
#define KD 64
#define NB 5
#define NRI_ 3
#define NRF_ 2

typedef short short8_t __attribute__((ext_vector_type(8)));
typedef float f32x4 __attribute__((ext_vector_type(4)));

__device__ __forceinline__ float sspf(float x) {
    float ax = fabsf(x);
    return fmaxf(x, 0.0f) + log1pf(__expf(-ax)) - 0.69314718055994530942f;
}

__device__ __forceinline__ short f2bf(float f) {
    unsigned u = __builtin_bit_cast(unsigned, f);
    u += 0x7FFF + ((u >> 16) & 1);          // RNE
    return (short)(u >> 16);
}

// One block per matrix: src [K][128] f32 -> dst [128][K] bf16 (transposed)
__global__ void transpose_weights(const float* __restrict__ src,
                                  short* __restrict__ dst, int K)
{
    const size_t mo = (size_t)blockIdx.x * K * 128;
    const float* s = src + mo;
    short* d = dst + mo;
    for (int e = threadIdx.x; e < K * 128; e += 256) {
        int k = e >> 7, n = e & 127;
        d[n * K + k] = f2bf(s[e]);
    }
}

// C[r,:] = post( pre(A[r,:]) @ W + bias ) [+ u*add]
// tile 64 rows x 128 cols, 256 threads = 4 waves, wave = 16 rows x 8 col-tiles
__launch_bounds__(256, 4)
__global__ void gemm_mfma(const float* __restrict__ A,
                          const short* __restrict__ WT,   // [128 n][128 k] bf16
                          const float* __restrict__ bias,
                          const float* __restrict__ add,
                          const float* __restrict__ uvec,
                          float* __restrict__ C,
                          int nrows, int preSSP, int postSSP)
{
    __shared__ short wt_s[128 * 136];       // [n][k], pad 8 shorts

    const int tid = threadIdx.x;
#pragma unroll
    for (int i = 0; i < 8; ++i) {
        int c = i * 256 + tid;              // 16B chunk, 2048 total
        int n = c >> 4;
        int kc = c & 15;
        *(short8_t*)&wt_s[n * 136 + kc * 8] = *(const short8_t*)&WT[n * 128 + kc * 8];
    }
    __syncthreads();

    const int lane = tid & 63;
    const int wv = tid >> 6;
    const int m = lane & 15;
    const int quad = lane >> 4;
    const int rowA = blockIdx.x * 64 + wv * 16 + m;       // A-fragment row

    f32x4 acc[8];
#pragma unroll
    for (int ct = 0; ct < 8; ++ct) acc[ct] = (f32x4){0.f, 0.f, 0.f, 0.f};

#pragma unroll
    for (int chunk = 0; chunk < 4; ++chunk) {
        float v[8];
        if (rowA < nrows) {
            const float* ap = A + (size_t)rowA * FD + chunk * 32 + quad * 8;
            float4 x0 = *(const float4*)ap;
            float4 x1 = *(const float4*)(ap + 4);
            v[0] = x0.x; v[1] = x0.y; v[2] = x0.z; v[3] = x0.w;
            v[4] = x1.x; v[5] = x1.y; v[6] = x1.z; v[7] = x1.w;
            if (preSSP) {
#pragma unroll
                for (int j = 0; j < 8; ++j) v[j] = sspf(v[j]);
            }
        } else {
#pragma unroll
            for (int j = 0; j < 8; ++j) v[j] = 0.f;
        }
        short8_t afr;
#pragma unroll
        for (int j = 0; j < 8; ++j) afr[j] = f2bf(v[j]);

#pragma unroll
        for (int ct = 0; ct < 8; ++ct) {
            short8_t bfr = *(short8_t*)&wt_s[(ct * 16 + m) * 136 + chunk * 32 + quad * 8];
            acc[ct] = __builtin_amdgcn_mfma_f32_16x16x32_bf16(afr, bfr, acc[ct], 0, 0, 0);
        }
    }

    // epilogue: D row = quad*4+reg, col = ct*16+m
    const int rbase = blockIdx.x * 64 + wv * 16 + quad * 4;
#pragma unroll
    for (int ct = 0; ct < 8; ++ct) {
        int cg = ct * 16 + m;
        float bv = bias[cg];
        float uvv = uvec ? uvec[cg] : 1.0f;
#pragma unroll
        for (int rg = 0; rg < 4; ++rg) {
            int r = rbase + rg;
            if (r >= nrows) continue;
            float vv = acc[ct][rg] + bv;
            if (postSSP) vv = sspf(vv);
            if (add) vv = fmaf(uvv, add[(size_t)r * FD + cg], vv);
            C[(size_t)r * FD + cg] = vv;
        }
    }
}

// g = (cutoff*rbf) @ Wg (MFMA) ; msg = g * xj[idx_j] ; segment-sum into m
__launch_bounds__(256, 2)
__global__ void pair_mfma(const float* __restrict__ rbfs,
                          const float* __restrict__ cutoffs,
                          const int* __restrict__ idx_i,
                          const int* __restrict__ idx_j,
                          const short* __restrict__ WgT,  // [128 n][64 k] bf16
                          const float* __restrict__ xj,
                          float* __restrict__ mout)
{
    __shared__ float g_s[128 * 132];        // 67584 B; first 18432 B aliased as WgT staging
    __shared__ int ii_s[128];
    __shared__ int jj_s[128];
    short* wt_s = (short*)g_s;              // [128 n][72 k]

    const int tid = threadIdx.x;
    const long long p0 = (long long)blockIdx.x * 128;

#pragma unroll
    for (int i = 0; i < 4; ++i) {
        int c = i * 256 + tid;              // 1024 chunks of 8 shorts
        int n = c >> 3;
        int kc = c & 7;
        *(short8_t*)&wt_s[n * 72 + kc * 8] = *(const short8_t*)&WgT[n * 64 + kc * 8];
    }
    if (tid < 128) {
        long long pg = p0 + tid;
        ii_s[tid] = (pg < NP) ? idx_i[pg] : -1;
        jj_s[tid] = (pg < NP) ? idx_j[pg] : 0;
    }
    __syncthreads();

    const int lane = tid & 63;
    const int wv = tid >> 6;
    const int m = lane & 15;
    const int quad = lane >> 4;

    f32x4 acc[2][8];
#pragma unroll
    for (int rt = 0; rt < 2; ++rt)
#pragma unroll
        for (int ct = 0; ct < 8; ++ct) acc[rt][ct] = (f32x4){0.f, 0.f, 0.f, 0.f};

#pragma unroll
    for (int chunk = 0; chunk < 2; ++chunk) {
        short8_t afr[2];
#pragma unroll
        for (int rt = 0; rt < 2; ++rt) {
            long long pg = p0 + wv * 32 + rt * 16 + m;
            float v[8];
            if (pg < NP) {
                const float* ap = rbfs + pg * KD + chunk * 32 + quad * 8;
                float4 x0 = *(const float4*)ap;
                float4 x1 = *(const float4*)(ap + 4);
                float cu = cutoffs[pg];
                v[0] = x0.x * cu; v[1] = x0.y * cu; v[2] = x0.z * cu; v[3] = x0.w * cu;
                v[4] = x1.x * cu; v[5] = x1.y * cu; v[6] = x1.z * cu; v[7] = x1.w * cu;
            } else {
#pragma unroll
                for (int j = 0; j < 8; ++j) v[j] = 0.f;
            }
#pragma unroll
            for (int j = 0; j < 8; ++j) afr[rt][j] = f2bf(v[j]);
        }
#pragma unroll
        for (int ct = 0; ct < 8; ++ct) {
            short8_t bfr = *(short8_t*)&wt_s[(ct * 16 + m) * 72 + chunk * 32 + quad * 8];
            acc[0][ct] = __builtin_amdgcn_mfma_f32_16x16x32_bf16(afr[0], bfr, acc[0][ct], 0, 0, 0);
            acc[1][ct] = __builtin_amdgcn_mfma_f32_16x16x32_bf16(afr[1], bfr, acc[1][ct], 0, 0, 0);
        }
    }
    __syncthreads();   // WgT staging reads complete; reuse LDS as g_s

    // spill g (C/D layout) to [pair][col] LDS
#pragma unroll
    for (int ct = 0; ct < 8; ++ct) {
        int cg = ct * 16 + m;
#pragma unroll
        for (int rt = 0; rt < 2; ++rt) {
            int pb = wv * 32 + rt * 16 + quad * 4;
#pragma unroll
            for (int rg = 0; rg < 4; ++rg)
                g_s[(pb + rg) * 132 + cg] = acc[rt][ct][rg];
        }
    }
    __syncthreads();

    // msg = g * xj[idx_j]  (float4 gathers, thread = 8 pairs x 8 cols)
    const int tx = tid & 15;
    const int ty = tid >> 4;
    const int c0 = tx * 4, c1 = c0 + 64;
#pragma unroll
    for (int i = 0; i < 8; ++i) {
        int p = ty + 16 * i;
        int jrow = jj_s[p];
        float4 xa = *(const float4*)&xj[(size_t)jrow * FD + c0];
        float4 xb = *(const float4*)&xj[(size_t)jrow * FD + c1];
        float4 ga = *(float4*)&g_s[p * 132 + c0];
        float4 gb = *(float4*)&g_s[p * 132 + c1];
        ga.x *= xa.x; ga.y *= xa.y; ga.z *= xa.z; ga.w *= xa.w;
        gb.x *= xb.x; gb.y *= xb.y; gb.z *= xb.z; gb.w *= xb.w;
        *(float4*)&g_s[p * 132 + c0] = ga;
        *(float4*)&g_s[p * 132 + c1] = gb;
    }
    __syncthreads();

    // segment-sum scan over sorted idx_i
    const int col = tid & 127;
    const int half = tid >> 7;
    const int ps = half * 64;
    float accum = 0.f;
    int cur = ii_s[ps];
    for (int q = 0; q < 64; ++q) {
        int a = ii_s[ps + q];
        if (a != cur) {
            if (cur >= 0) atomicAdd(&mout[(size_t)cur * FD + col], accum);
            accum = 0.f;
            cur = a;
        }
        accum += g_s[(ps + q) * 132 + col];
    }
    if (cur >= 0) atomicAdd(&mout[(size_t)cur * FD + col], accum);
}

extern "C" void kernel_launch(void* const* d_in, const int* in_sizes, int n_in,
                              void* d_out, int out_size, void* d_ws, size_t ws_size,
                              hipStream_t stream)
{
    const float* features = (const float*)d_in[0];
    const float* cutoffs  = (const float*)d_in[1];
    const float* rbfs     = (const float*)d_in[2];
    const int*   idx_i    = (const int*)d_in[3];
    const int*   idx_j    = (const int*)d_in[4];
    const float* Wg   = (const float*)d_in[5];
    const float* Wi   = (const float*)d_in[6];
    const float* bi   = (const float*)d_in[7];
    const float* Wj   = (const float*)d_in[8];
    const float* bj   = (const float*)d_in[9];
    const float* Wr1  = (const float*)d_in[10];
    const float* br1  = (const float*)d_in[11];
    const float* Wr2  = (const float*)d_in[12];
    const float* br2  = (const float*)d_in[13];
    const float* Wout = (const float*)d_in[14];
    const float* bout = (const float*)d_in[15];
    const float* u    = (const float*)d_in[16];
    const float* Wf1  = (const float*)d_in[17];
    const float* bf1  = (const float*)d_in[18];
    const float* Wf2  = (const float*)d_in[19];
    const float* bf2  = (const float*)d_in[20];
    float* out = (float*)d_out;

    const size_t NF = (size_t)NA * FD;
    const size_t MS = (size_t)FD * FD;      // 16384
    float* mbuf = (float*)d_ws;
    float* tbuf = mbuf + NF;
    short* wtb  = (short*)(tbuf + NF);      // 65 transposed bf16 128x128 mats
    short* wgt  = wtb + 65 * MS;            // 5 transposed bf16 128x64 mats
    float* xjbuf = out + 4 * NF;            // out[4] slice unused until b=4 gated update

    // ---- pre-transpose weights to bf16 [n][k] ----
    transpose_weights<<<5,  256, 0, stream>>>(Wi,   wtb +  0 * MS, 128);
    transpose_weights<<<5,  256, 0, stream>>>(Wj,   wtb +  5 * MS, 128);
    transpose_weights<<<15, 256, 0, stream>>>(Wr1,  wtb + 10 * MS, 128);
    transpose_weights<<<15, 256, 0, stream>>>(Wr2,  wtb + 25 * MS, 128);
    transpose_weights<<<5,  256, 0, stream>>>(Wout, wtb + 40 * MS, 128);
    transpose_weights<<<10, 256, 0, stream>>>(Wf1,  wtb + 45 * MS, 128);
    transpose_weights<<<10, 256, 0, stream>>>(Wf2,  wtb + 55 * MS, 128);
    transpose_weights<<<5,  256, 0, stream>>>(Wg,   wgt, 64);

    const int gA = (NA + 63) / 64;          // 782
    const int gP = (NP + 127) / 128;        // 7813
    dim3 blk(256);

    const float* x = features;
    for (int b = 0; b < NB; ++b) {
        const short* WiT = wtb + (0 + b) * MS;
        const short* WjT = wtb + (5 + b) * MS;
        const short* WoT = wtb + (40 + b) * MS;
        const short* WgT = wgt + (size_t)b * FD * KD;
        const float* bi_b = bi + (size_t)b * FD;
        const float* bj_b = bj + (size_t)b * FD;
        const float* bout_b = bout + (size_t)b * FD;
        const float* u_b = u + (size_t)b * FD;
        float* xout = out + (size_t)b * NF;

        gemm_mfma<<<gA, blk, 0, stream>>>(x, WiT, bi_b, nullptr, nullptr, mbuf, NA, 1, 1);
        gemm_mfma<<<gA, blk, 0, stream>>>(x, WjT, bj_b, nullptr, nullptr, xjbuf, NA, 1, 1);
        pair_mfma<<<gP, blk, 0, stream>>>(rbfs, cutoffs, idx_i, idx_j, WgT, xjbuf, mbuf);
        for (int r = 0; r < NRI_; ++r) {
            const short* W1T = wtb + (10 + b * NRI_ + r) * MS;
            const short* W2T = wtb + (25 + b * NRI_ + r) * MS;
            const float* b1 = br1 + ((size_t)b * NRI_ + r) * FD;
            const float* b2 = br2 + ((size_t)b * NRI_ + r) * FD;
            gemm_mfma<<<gA, blk, 0, stream>>>(mbuf, W1T, b1, nullptr, nullptr, tbuf, NA, 1, 1);
            gemm_mfma<<<gA, blk, 0, stream>>>(tbuf, W2T, b2, mbuf, nullptr, mbuf, NA, 0, 0);
        }
        gemm_mfma<<<gA, blk, 0, stream>>>(mbuf, WoT, bout_b, x, u_b, xout, NA, 1, 0);
        for (int r = 0; r < NRF_; ++r) {
            const short* W1T = wtb + (45 + b * NRF_ + r) * MS;
            const short* W2T = wtb + (55 + b * NRF_ + r) * MS;
            const float* b1 = bf1 + ((size_t)b * NRF_ + r) * FD;
            const float* b2 = bf2 + ((size_t)b * NRF_ + r) * FD;
            gemm_mfma<<<gA, blk, 0, stream>>>(xout, W1T, b1, nullptr, nullptr, tbuf, NA, 1, 1);
            gemm_mfma<<<gA, blk, 0, stream>>>(tbuf, W2T, b2, xout, nullptr, xout, NA, 0, 0);
        }
        x = xout;
    }
}

// Round 3
// 3292.349 us; speedup vs baseline: 1.7045x; 1.2967x over previous
//
#include <hip/hip_runtime.h>
#include <math.h>

#define NA 50000
#define NP 1000000
#define FD 128
#define KD 64
#define NB 5
#define NRI_ 3
#define NRF_ 2

typedef short short8_t __attribute__((ext_vector_type(8)));
typedef short short4_t __attribute__((ext_vector_type(4)));
typedef float f32x4 __attribute__((ext_vector_type(4)));

__device__ __forceinline__ float sspf(float x) {
    float ax = fabsf(x);
    return fmaxf(x, 0.0f) + log1pf(__expf(-ax)) - 0.69314718055994530942f;
}

__device__ __forceinline__ short f2bf(float f) {
    unsigned u = __builtin_bit_cast(unsigned, f);
    u += 0x7FFF + ((u >> 16) & 1);          // RNE
    return (short)(u >> 16);
}

// One block per matrix: src [K][128] f32 -> dst [128][K] bf16 (transposed)
__global__ void transpose_weights(const float* __restrict__ src,
                                  short* __restrict__ dst, int K)
{
    const size_t mo = (size_t)blockIdx.x * K * 128;
    const float* s = src + mo;
    short* d = dst + mo;
    for (int e = threadIdx.x; e < K * 128; e += 256) {
        int k = e >> 7, n = e & 127;
        d[n * K + k] = f2bf(s[e]);
    }
}

// stage one [128 n][128 k] bf16 weight into wt_s [128][136]
__device__ __forceinline__ void stage_wt(const short* __restrict__ WT,
                                         short* wt_s, int tid)
{
#pragma unroll
    for (int i = 0; i < 8; ++i) {
        int c = i * 256 + tid;              // 2048 chunks of 16B
        int n = c >> 4, kc = c & 15;
        *(short8_t*)&wt_s[n * 136 + kc * 8] = *(const short8_t*)&WT[n * 128 + kc * 8];
    }
}

// acc += actw(16 rows bf16) @ wt_s(128x128 bf16)
__device__ __forceinline__ void gemm16(const short* actw, const short* wt_s,
                                       int mI, int quad, f32x4 acc[8])
{
#pragma unroll
    for (int ch = 0; ch < 4; ++ch) {
        short8_t a = *(const short8_t*)&actw[mI * 136 + ch * 32 + quad * 8];
#pragma unroll
        for (int ct = 0; ct < 8; ++ct) {
            short8_t bf = *(const short8_t*)&wt_s[(ct * 16 + mI) * 136 + ch * 32 + quad * 8];
            acc[ct] = __builtin_amdgcn_mfma_f32_16x16x32_bf16(a, bf, acc[ct], 0, 0, 0);
        }
    }
}

// xi = ssp(ssp(x)@Wi + bi), xj = ssp(ssp(x)@Wj + bj)   (x read once)
__launch_bounds__(256, 3)
__global__ void pre_kernel(const float* __restrict__ x,
                           const short* __restrict__ WiT, const float* __restrict__ bi_,
                           const short* __restrict__ WjT, const float* __restrict__ bj_,
                           float* __restrict__ xi_out, float* __restrict__ xj_out)
{
    __shared__ short act_s[64 * 136];
    __shared__ short wt_s[128 * 136];
    const int tid = threadIdx.x;
    const int lane = tid & 63, wv = tid >> 6;
    const int mI = lane & 15, quad = lane >> 4;
    const short* actw = act_s + wv * 16 * 136;
    const int row0 = blockIdx.x * 64;
    const int rowrd = row0 + wv * 16 + quad * 4;

    // coalesced: act_s = bf16(ssp(x))
#pragma unroll
    for (int i = 0; i < 8; ++i) {
        int f = i * 256 + tid;              // 2048 float4 chunks
        int rr = f >> 5;
        int c4 = (f & 31) * 4;
        float4 v = make_float4(0.f, 0.f, 0.f, 0.f);
        if (row0 + rr < NA) v = *(const float4*)&x[(size_t)(row0 + rr) * FD + c4];
        short4_t s;
        s[0] = f2bf(sspf(v.x)); s[1] = f2bf(sspf(v.y));
        s[2] = f2bf(sspf(v.z)); s[3] = f2bf(sspf(v.w));
        *(short4_t*)&act_s[rr * 136 + c4] = s;
    }
    stage_wt(WiT, wt_s, tid);
    __syncthreads();

    f32x4 acc[8];
#pragma unroll
    for (int ct = 0; ct < 8; ++ct) acc[ct] = (f32x4){0.f, 0.f, 0.f, 0.f};
    gemm16(actw, wt_s, mI, quad, acc);
#pragma unroll
    for (int ct = 0; ct < 8; ++ct) {
        float bb = bi_[ct * 16 + mI];
#pragma unroll
        for (int rg = 0; rg < 4; ++rg) {
            int r = rowrd + rg;
            if (r < NA) xi_out[(size_t)r * FD + ct * 16 + mI] = sspf(acc[ct][rg] + bb);
        }
    }
    __syncthreads();
    stage_wt(WjT, wt_s, tid);
    __syncthreads();
#pragma unroll
    for (int ct = 0; ct < 8; ++ct) acc[ct] = (f32x4){0.f, 0.f, 0.f, 0.f};
    gemm16(actw, wt_s, mI, quad, acc);
#pragma unroll
    for (int ct = 0; ct < 8; ++ct) {
        float bb = bj_[ct * 16 + mI];
#pragma unroll
        for (int rg = 0; rg < 4; ++rg) {
            int r = rowrd + rg;
            if (r < NA) xj_out[(size_t)r * FD + ct * 16 + mI] = sspf(acc[ct][rg] + bb);
        }
    }
}

// whole post-scatter atom chain: 3 interaction residuals, gated update, 2 feature residuals
__launch_bounds__(256, 3)
__global__ void chain_kernel(const float* __restrict__ xprev,
                             const float* __restrict__ mbuf,
                             const short* __restrict__ Wr1T, const float* __restrict__ br1_,
                             const short* __restrict__ Wr2T, const float* __restrict__ br2_,
                             const short* __restrict__ WoT,  const float* __restrict__ bo_,
                             const float* __restrict__ u_,
                             const short* __restrict__ Wf1T, const float* __restrict__ bf1_,
                             const short* __restrict__ Wf2T, const float* __restrict__ bf2_,
                             float* __restrict__ xout)
{
    __shared__ short act_s[64 * 136];
    __shared__ short wt_s[128 * 136];
    const int tid = threadIdx.x;
    const int lane = tid & 63, wv = tid >> 6;
    const int mI = lane & 15, quad = lane >> 4;
    short* actw = act_s + wv * 16 * 136;    // wave-private rows
    const int rowrd = blockIdx.x * 64 + wv * 16 + quad * 4;

    float mreg[8][4];
#pragma unroll
    for (int ct = 0; ct < 8; ++ct)
#pragma unroll
        for (int rg = 0; rg < 4; ++rg) {
            int r = rowrd + rg;
            mreg[ct][rg] = (r < NA) ? mbuf[(size_t)r * FD + ct * 16 + mI] : 0.f;
        }

    f32x4 acc[8];

    // ---- interaction residuals: m = m + ssp(ssp(m)@W1+b1)@W2 + b2 ----
    for (int r = 0; r < NRI_; ++r) {
        __syncthreads();
        stage_wt(Wr1T + (size_t)r * FD * FD, wt_s, tid);
#pragma unroll
        for (int ct = 0; ct < 8; ++ct)
#pragma unroll
            for (int rg = 0; rg < 4; ++rg)
                actw[(quad * 4 + rg) * 136 + ct * 16 + mI] = f2bf(sspf(mreg[ct][rg]));
        __syncthreads();
#pragma unroll
        for (int ct = 0; ct < 8; ++ct) acc[ct] = (f32x4){0.f, 0.f, 0.f, 0.f};
        gemm16(actw, wt_s, mI, quad, acc);

        __syncthreads();
        stage_wt(Wr2T + (size_t)r * FD * FD, wt_s, tid);
#pragma unroll
        for (int ct = 0; ct < 8; ++ct) {
            float b1 = br1_[r * FD + ct * 16 + mI];
#pragma unroll
            for (int rg = 0; rg < 4; ++rg)
                actw[(quad * 4 + rg) * 136 + ct * 16 + mI] = f2bf(sspf(acc[ct][rg] + b1));
        }
        __syncthreads();
#pragma unroll
        for (int ct = 0; ct < 8; ++ct) acc[ct] = (f32x4){0.f, 0.f, 0.f, 0.f};
        gemm16(actw, wt_s, mI, quad, acc);
#pragma unroll
        for (int ct = 0; ct < 8; ++ct) {
            float b2 = br2_[r * FD + ct * 16 + mI];
#pragma unroll
            for (int rg = 0; rg < 4; ++rg)
                mreg[ct][rg] += acc[ct][rg] + b2;
        }
    }

    // ---- gated update: x = u*xprev + ssp(m)@Wout + bout ----
    __syncthreads();
    stage_wt(WoT, wt_s, tid);
#pragma unroll
    for (int ct = 0; ct < 8; ++ct)
#pragma unroll
        for (int rg = 0; rg < 4; ++rg)
            actw[(quad * 4 + rg) * 136 + ct * 16 + mI] = f2bf(sspf(mreg[ct][rg]));
    __syncthreads();
#pragma unroll
    for (int ct = 0; ct < 8; ++ct) acc[ct] = (f32x4){0.f, 0.f, 0.f, 0.f};
    gemm16(actw, wt_s, mI, quad, acc);

    float xreg[8][4];
#pragma unroll
    for (int ct = 0; ct < 8; ++ct) {
        float bo = bo_[ct * 16 + mI];
        float uu = u_[ct * 16 + mI];
#pragma unroll
        for (int rg = 0; rg < 4; ++rg) {
            int r = rowrd + rg;
            float xp = (r < NA) ? xprev[(size_t)r * FD + ct * 16 + mI] : 0.f;
            xreg[ct][rg] = fmaf(uu, xp, acc[ct][rg] + bo);
        }
    }

    // ---- feature residuals: x = x + ssp(ssp(x)@Wf1+bf1)@Wf2 + bf2 ----
    for (int r = 0; r < NRF_; ++r) {
        __syncthreads();
        stage_wt(Wf1T + (size_t)r * FD * FD, wt_s, tid);
#pragma unroll
        for (int ct = 0; ct < 8; ++ct)
#pragma unroll
            for (int rg = 0; rg < 4; ++rg)
                actw[(quad * 4 + rg) * 136 + ct * 16 + mI] = f2bf(sspf(xreg[ct][rg]));
        __syncthreads();
#pragma unroll
        for (int ct = 0; ct < 8; ++ct) acc[ct] = (f32x4){0.f, 0.f, 0.f, 0.f};
        gemm16(actw, wt_s, mI, quad, acc);

        __syncthreads();
        stage_wt(Wf2T + (size_t)r * FD * FD, wt_s, tid);
#pragma unroll
        for (int ct = 0; ct < 8; ++ct) {
            float b1 = bf1_[r * FD + ct * 16 + mI];
#pragma unroll
            for (int rg = 0; rg < 4; ++rg)
                actw[(quad * 4 + rg) * 136 + ct * 16 + mI] = f2bf(sspf(acc[ct][rg] + b1));
        }
        __syncthreads();
#pragma unroll
        for (int ct = 0; ct < 8; ++ct) acc[ct] = (f32x4){0.f, 0.f, 0.f, 0.f};
        gemm16(actw, wt_s, mI, quad, acc);
#pragma unroll
        for (int ct = 0; ct < 8; ++ct) {
            float b2 = bf2_[r * FD + ct * 16 + mI];
#pragma unroll
            for (int rg = 0; rg < 4; ++rg)
                xreg[ct][rg] += acc[ct][rg] + b2;
        }
    }

#pragma unroll
    for (int ct = 0; ct < 8; ++ct)
#pragma unroll
        for (int rg = 0; rg < 4; ++rg) {
            int r = rowrd + rg;
            if (r < NA) xout[(size_t)r * FD + ct * 16 + mI] = xreg[ct][rg];
        }
}

// g = (cutoff*rbf) @ Wg (MFMA) ; msg = g * xj[idx_j] ; segment-sum into m  (unchanged)
__launch_bounds__(256, 2)
__global__ void pair_mfma(const float* __restrict__ rbfs,
                          const float* __restrict__ cutoffs,
                          const int* __restrict__ idx_i,
                          const int* __restrict__ idx_j,
                          const short* __restrict__ WgT,  // [128 n][64 k] bf16
                          const float* __restrict__ xj,
                          float* __restrict__ mout)
{
    __shared__ float g_s[128 * 132];
    __shared__ int ii_s[128];
    __shared__ int jj_s[128];
    short* wt_s = (short*)g_s;              // [128 n][72 k]

    const int tid = threadIdx.x;
    const long long p0 = (long long)blockIdx.x * 128;

#pragma unroll
    for (int i = 0; i < 4; ++i) {
        int c = i * 256 + tid;
        int n = c >> 3;
        int kc = c & 7;
        *(short8_t*)&wt_s[n * 72 + kc * 8] = *(const short8_t*)&WgT[n * 64 + kc * 8];
    }
    if (tid < 128) {
        long long pg = p0 + tid;
        ii_s[tid] = (pg < NP) ? idx_i[pg] : -1;
        jj_s[tid] = (pg < NP) ? idx_j[pg] : 0;
    }
    __syncthreads();

    const int lane = tid & 63;
    const int wv = tid >> 6;
    const int m = lane & 15;
    const int quad = lane >> 4;

    f32x4 acc[2][8];
#pragma unroll
    for (int rt = 0; rt < 2; ++rt)
#pragma unroll
        for (int ct = 0; ct < 8; ++ct) acc[rt][ct] = (f32x4){0.f, 0.f, 0.f, 0.f};

#pragma unroll
    for (int chunk = 0; chunk < 2; ++chunk) {
        short8_t afr[2];
#pragma unroll
        for (int rt = 0; rt < 2; ++rt) {
            long long pg = p0 + wv * 32 + rt * 16 + m;
            float v[8];
            if (pg < NP) {
                const float* ap = rbfs + pg * KD + chunk * 32 + quad * 8;
                float4 x0 = *(const float4*)ap;
                float4 x1 = *(const float4*)(ap + 4);
                float cu = cutoffs[pg];
                v[0] = x0.x * cu; v[1] = x0.y * cu; v[2] = x0.z * cu; v[3] = x0.w * cu;
                v[4] = x1.x * cu; v[5] = x1.y * cu; v[6] = x1.z * cu; v[7] = x1.w * cu;
            } else {
#pragma unroll
                for (int j = 0; j < 8; ++j) v[j] = 0.f;
            }
#pragma unroll
            for (int j = 0; j < 8; ++j) afr[rt][j] = f2bf(v[j]);
        }
#pragma unroll
        for (int ct = 0; ct < 8; ++ct) {
            short8_t bfr = *(short8_t*)&wt_s[(ct * 16 + m) * 72 + chunk * 32 + quad * 8];
            acc[0][ct] = __builtin_amdgcn_mfma_f32_16x16x32_bf16(afr[0], bfr, acc[0][ct], 0, 0, 0);
            acc[1][ct] = __builtin_amdgcn_mfma_f32_16x16x32_bf16(afr[1], bfr, acc[1][ct], 0, 0, 0);
        }
    }
    __syncthreads();

#pragma unroll
    for (int ct = 0; ct < 8; ++ct) {
        int cg = ct * 16 + m;
#pragma unroll
        for (int rt = 0; rt < 2; ++rt) {
            int pb = wv * 32 + rt * 16 + quad * 4;
#pragma unroll
            for (int rg = 0; rg < 4; ++rg)
                g_s[(pb + rg) * 132 + cg] = acc[rt][ct][rg];
        }
    }
    __syncthreads();

    const int tx = tid & 15;
    const int ty = tid >> 4;
    const int c0 = tx * 4, c1 = c0 + 64;
#pragma unroll
    for (int i = 0; i < 8; ++i) {
        int p = ty + 16 * i;
        int jrow = jj_s[p];
        float4 xa = *(const float4*)&xj[(size_t)jrow * FD + c0];
        float4 xb = *(const float4*)&xj[(size_t)jrow * FD + c1];
        float4 ga = *(float4*)&g_s[p * 132 + c0];
        float4 gb = *(float4*)&g_s[p * 132 + c1];
        ga.x *= xa.x; ga.y *= xa.y; ga.z *= xa.z; ga.w *= xa.w;
        gb.x *= xb.x; gb.y *= xb.y; gb.z *= xb.z; gb.w *= xb.w;
        *(float4*)&g_s[p * 132 + c0] = ga;
        *(float4*)&g_s[p * 132 + c1] = gb;
    }
    __syncthreads();

    const int col = tid & 127;
    const int half = tid >> 7;
    const int ps = half * 64;
    float accum = 0.f;
    int cur = ii_s[ps];
    for (int q = 0; q < 64; ++q) {
        int a = ii_s[ps + q];
        if (a != cur) {
            if (cur >= 0) atomicAdd(&mout[(size_t)cur * FD + col], accum);
            accum = 0.f;
            cur = a;
        }
        accum += g_s[(ps + q) * 132 + col];
    }
    if (cur >= 0) atomicAdd(&mout[(size_t)cur * FD + col], accum);
}

extern "C" void kernel_launch(void* const* d_in, const int* in_sizes, int n_in,
                              void* d_out, int out_size, void* d_ws, size_t ws_size,
                              hipStream_t stream)
{
    const float* features = (const float*)d_in[0];
    const float* cutoffs  = (const float*)d_in[1];
    const float* rbfs     = (const float*)d_in[2];
    const int*   idx_i    = (const int*)d_in[3];
    const int*   idx_j    = (const int*)d_in[4];
    const float* Wg   = (const float*)d_in[5];
    const float* Wi   = (const float*)d_in[6];
    const float* bi   = (const float*)d_in[7];
    const float* Wj   = (const float*)d_in[8];
    const float* bj   = (const float*)d_in[9];
    const float* Wr1  = (const float*)d_in[10];
    const float* br1  = (const float*)d_in[11];
    const float* Wr2  = (const float*)d_in[12];
    const float* br2  = (const float*)d_in[13];
    const float* Wout = (const float*)d_in[14];
    const float* bout = (const float*)d_in[15];
    const float* u    = (const float*)d_in[16];
    const float* Wf1  = (const float*)d_in[17];
    const float* bf1  = (const float*)d_in[18];
    const float* Wf2  = (const float*)d_in[19];
    const float* bf2  = (const float*)d_in[20];
    float* out = (float*)d_out;

    const size_t NF = (size_t)NA * FD;
    const size_t MS = (size_t)FD * FD;
    float* mbuf = (float*)d_ws;
    short* wtb  = (short*)(mbuf + NF);
    short* wgt  = wtb + 65 * MS;
    float* xjbuf = out + 4 * NF;            // out[4] slice: free until b=4's chain write

    transpose_weights<<<5,  256, 0, stream>>>(Wi,   wtb +  0 * MS, 128);
    transpose_weights<<<5,  256, 0, stream>>>(Wj,   wtb +  5 * MS, 128);
    transpose_weights<<<15, 256, 0, stream>>>(Wr1,  wtb + 10 * MS, 128);
    transpose_weights<<<15, 256, 0, stream>>>(Wr2,  wtb + 25 * MS, 128);
    transpose_weights<<<5,  256, 0, stream>>>(Wout, wtb + 40 * MS, 128);
    transpose_weights<<<10, 256, 0, stream>>>(Wf1,  wtb + 45 * MS, 128);
    transpose_weights<<<10, 256, 0, stream>>>(Wf2,  wtb + 55 * MS, 128);
    transpose_weights<<<5,  256, 0, stream>>>(Wg,   wgt, 64);

    const int gA = (NA + 63) / 64;          // 782
    const int gP = (NP + 127) / 128;        // 7813
    dim3 blk(256);

    const float* x = features;
    for (int b = 0; b < NB; ++b) {
        float* xout = out + (size_t)b * NF;

        pre_kernel<<<gA, blk, 0, stream>>>(x,
            wtb + (0 + b) * MS, bi + (size_t)b * FD,
            wtb + (5 + b) * MS, bj + (size_t)b * FD,
            mbuf, xjbuf);
        pair_mfma<<<gP, blk, 0, stream>>>(rbfs, cutoffs, idx_i, idx_j,
            wgt + (size_t)b * FD * KD, xjbuf, mbuf);
        chain_kernel<<<gA, blk, 0, stream>>>(x, mbuf,
            wtb + (10 + b * NRI_) * MS, br1 + (size_t)b * NRI_ * FD,
            wtb + (25 + b * NRI_) * MS, br2 + (size_t)b * NRI_ * FD,
            wtb + (40 + b) * MS, bout + (size_t)b * FD, u + (size_t)b * FD,
            wtb + (45 + b * NRF_) * MS, bf1 + (size_t)b * NRF_ * FD,
            wtb + (55 + b * NRF_) * MS, bf2 + (size_t)b * NRF_ * FD,
            xout);
        x = xout;
    }
}